// Round 2
// baseline (242.010 us; speedup 1.0000x reference)
//
#include <hip/hip_runtime.h>

// out[m][e*5+c] = x[m,c]*w_c[e] + (b_c[e] + ot[c][e]);  M=65536, E=512
// Pure HBM-write-bound (640 MiB f32 out). Round-1 lesson: per-iteration
// __syncthreads() forces s_waitcnt vmcnt(0) drains of the store stream
// (compiler barrier semantics) -> 4.9 TB/s vs fill kernel's 6.7 TB/s.
// Round-2 structure: NO barriers / NO LDS in the main loop.
//   - thread t owns output words 4t..4t+3 of every row (contiguous 16B slot)
//   - its 4 (w, b+ot) table values are row-invariant -> gathered once from an
//     LDS-staged combined table (single barrier at kernel start)
//   - main loop: 4 broadcast x loads (block shares one row) + 4 FMA +
//     1 coalesced global_store_dwordx4.  Streams like fillBuffer.

#define ROWS_PER_BLOCK 32
#define THREADS 640            // 10 waves; one float4 slot per thread per row

__global__ __launch_bounds__(THREADS) void pc_kernel(
    const float* __restrict__ x,
    const float* __restrict__ w_bet,  const float* __restrict__ b_bet,
    const float* __restrict__ w_stk,  const float* __restrict__ b_stk,
    const float* __restrict__ w_call, const float* __restrict__ b_call,
    const float* __restrict__ w_odds, const float* __restrict__ b_odds,
    const float* __restrict__ ot,
    float* __restrict__ out)
{
    __shared__ float tw[2560];   // tw[c*512+e] = w_c[e]
    __shared__ float tb[2560];   // tb[c*512+e] = b_c[e] + ot[c][e]

    const int tid = threadIdx.x;

    // ---- one-time: stage combined tables into LDS (coalesced float4) ----
    {
        const int c  = tid >> 7;          // 0..4, uniform within each wave
        const int e0 = (tid & 127) * 4;
        const float* wp; const float* bp;
        if      (c == 0) { wp = w_bet;  bp = b_bet;  }
        else if (c == 1) { wp = w_stk;  bp = b_stk;  }
        else if (c == 2) { wp = w_stk;  bp = b_stk;  }
        else if (c == 3) { wp = w_call; bp = b_call; }
        else             { wp = w_odds; bp = b_odds; }
        float4 w4 = *reinterpret_cast<const float4*>(wp + e0);
        float4 b4 = *reinterpret_cast<const float4*>(bp + e0);
        float4 o4 = *reinterpret_cast<const float4*>(ot + c * 512 + e0);
        *reinterpret_cast<float4*>(tw + c * 512 + e0) = w4;
        float4 bb;
        bb.x = b4.x + o4.x; bb.y = b4.y + o4.y;
        bb.z = b4.z + o4.z; bb.w = b4.w + o4.w;
        *reinterpret_cast<float4*>(tb + c * 512 + e0) = bb;
    }
    __syncthreads();             // the ONLY barrier in the kernel

    // ---- per-thread row-invariant (e,c) + table values for words 4t+j ----
    float wv[4], bv[4];
    int   cj[4];
#pragma unroll
    for (int j = 0; j < 4; ++j) {
        int w = 4 * tid + j;     // output word within a row, 0..2559
        int e = w / 5;           // magic-mul division (setup only)
        int c = w - 5 * e;
        cj[j] = c;               // fully unrolled -> stays in registers
        wv[j] = tw[c * 512 + e];
        bv[j] = tb[c * 512 + e];
    }

    const int m_base = blockIdx.x * ROWS_PER_BLOCK;
    float4* outv = reinterpret_cast<float4*>(out);

#pragma unroll 4
    for (int r = 0; r < ROWS_PER_BLOCK; ++r) {
        const int m = m_base + r;
        const float* xr = x + m * 5;     // whole block on one row: 1 cacheline
        float4 v;
        v.x = fmaf(xr[cj[0]], wv[0], bv[0]);
        v.y = fmaf(xr[cj[1]], wv[1], bv[1]);
        v.z = fmaf(xr[cj[2]], wv[2], bv[2]);
        v.w = fmaf(xr[cj[3]], wv[3], bv[3]);
        outv[(size_t)m * 640 + tid] = v;  // contiguous 10 KB per block-row
    }
}

extern "C" void kernel_launch(void* const* d_in, const int* in_sizes, int n_in,
                              void* d_out, int out_size, void* d_ws, size_t ws_size,
                              hipStream_t stream) {
    const float* x      = (const float*)d_in[0];
    const float* w_bet  = (const float*)d_in[1];
    const float* b_bet  = (const float*)d_in[2];
    const float* w_stk  = (const float*)d_in[3];
    const float* b_stk  = (const float*)d_in[4];
    const float* w_call = (const float*)d_in[5];
    const float* b_call = (const float*)d_in[6];
    const float* w_odds = (const float*)d_in[7];
    const float* b_odds = (const float*)d_in[8];
    const float* ot     = (const float*)d_in[9];
    float* out = (float*)d_out;

    const int M    = in_sizes[0] / 5;          // 65536
    const int grid = M / ROWS_PER_BLOCK;       // 2048 blocks x 10 waves

    pc_kernel<<<grid, THREADS, 0, stream>>>(x, w_bet, b_bet, w_stk, b_stk,
                                            w_call, b_call, w_odds, b_odds,
                                            ot, out);
}

// Round 4
// 130.912 us; speedup vs baseline: 1.8486x; 1.8486x over previous
//
#include <hip/hip_runtime.h>

// out[m][e*5+c] = x[m,c]*w_c[e] + (b_c[e] + ot[c][e]);  M=65536, E=512
// Pure HBM-write-bound (640 MiB f32 out). Lessons so far:
//   R1 (136us): LDS-stage + barrier per 2 rows -> vmcnt(0) drain at each
//               s_barrier throttles the store stream (4.9 TB/s).
//   R2 (242us): interleaved global x-loads + stores share the IN-ORDER vmcnt
//               counter -> waiting for a row's loads drains all prior stores.
//   R3: timed out at the process level with no test output -- presumed infra
//       flake (no hang mechanism in the kernel). Same structure, resubmitted
//       with moderate unroll instead of full 32-way.
// Structure: main loop contains ONLY stores in the vmcnt stream.
//   - one-time prologue stages tables AND the block's x slice (640 B) in LDS
//   - per row: 4 ds_read_b32 (lgkmcnt, 5-word broadcast, conflict-free)
//     + 4 FMA + 1 coalesced global_store_dwordx4
//   - no barriers in the loop; vmcnt never waited on inside the loop.

#define ROWS 32
#define THREADS 640            // 10 waves; one float4 output slot per thread

__global__ __launch_bounds__(THREADS) void pc_kernel(
    const float* __restrict__ x,
    const float* __restrict__ w_bet,  const float* __restrict__ b_bet,
    const float* __restrict__ w_stk,  const float* __restrict__ b_stk,
    const float* __restrict__ w_call, const float* __restrict__ b_call,
    const float* __restrict__ w_odds, const float* __restrict__ b_odds,
    const float* __restrict__ ot,
    float* __restrict__ out)
{
    __shared__ float tw[2560];          // tw[c*512+e] = w_c[e]
    __shared__ float tb[2560];          // tb[c*512+e] = b_c[e] + ot[c][e]
    __shared__ float xl[ROWS * 5];      // block's x slice (160 floats)

    const int tid = threadIdx.x;

    // ---- one-time staging (the only barrier in the kernel) ----
    {
        const int c  = tid >> 7;        // 0..4
        const int e0 = (tid & 127) * 4;
        const float* wp; const float* bp;
        if      (c == 0) { wp = w_bet;  bp = b_bet;  }
        else if (c == 1) { wp = w_stk;  bp = b_stk;  }
        else if (c == 2) { wp = w_stk;  bp = b_stk;  }
        else if (c == 3) { wp = w_call; bp = b_call; }
        else             { wp = w_odds; bp = b_odds; }
        float4 w4 = *reinterpret_cast<const float4*>(wp + e0);
        float4 b4 = *reinterpret_cast<const float4*>(bp + e0);
        float4 o4 = *reinterpret_cast<const float4*>(ot + c * 512 + e0);
        *reinterpret_cast<float4*>(tw + c * 512 + e0) = w4;
        float4 bb;
        bb.x = b4.x + o4.x; bb.y = b4.y + o4.y;
        bb.z = b4.z + o4.z; bb.w = b4.w + o4.w;
        *reinterpret_cast<float4*>(tb + c * 512 + e0) = bb;

        if (tid < ROWS * 5 / 4)         // 40 threads stage the x slice
            reinterpret_cast<float4*>(xl)[tid] =
                reinterpret_cast<const float4*>(x)[blockIdx.x * (ROWS * 5 / 4) + tid];
    }
    __syncthreads();

    // ---- per-thread row-invariant table values for output words 4t..4t+3 ----
    float wv[4], bv[4];
    int   cj[4];
#pragma unroll
    for (int j = 0; j < 4; ++j) {
        int w = 4 * tid + j;            // word within a row, 0..2559
        int e = w / 5;                  // magic-mul (setup only)
        int c = w - 5 * e;
        cj[j] = c;
        wv[j] = tw[c * 512 + e];
        bv[j] = tb[c * 512 + e];
    }

    const int m_base = blockIdx.x * ROWS;
    float4* outv = reinterpret_cast<float4*>(out);
    const size_t obase = (size_t)m_base * 640 + tid;

#pragma unroll 8
    for (int r = 0; r < ROWS; ++r) {
        const float* xr = xl + r * 5;   // LDS row (lgkmcnt path, broadcast)
        float4 v;
        v.x = fmaf(xr[cj[0]], wv[0], bv[0]);
        v.y = fmaf(xr[cj[1]], wv[1], bv[1]);
        v.z = fmaf(xr[cj[2]], wv[2], bv[2]);
        v.w = fmaf(xr[cj[3]], wv[3], bv[3]);
        outv[obase + (size_t)r * 640] = v;      // pure store stream
    }
}

extern "C" void kernel_launch(void* const* d_in, const int* in_sizes, int n_in,
                              void* d_out, int out_size, void* d_ws, size_t ws_size,
                              hipStream_t stream) {
    const float* x      = (const float*)d_in[0];
    const float* w_bet  = (const float*)d_in[1];
    const float* b_bet  = (const float*)d_in[2];
    const float* w_stk  = (const float*)d_in[3];
    const float* b_stk  = (const float*)d_in[4];
    const float* w_call = (const float*)d_in[5];
    const float* b_call = (const float*)d_in[6];
    const float* w_odds = (const float*)d_in[7];
    const float* b_odds = (const float*)d_in[8];
    const float* ot     = (const float*)d_in[9];
    float* out = (float*)d_out;

    const int M    = in_sizes[0] / 5;   // 65536
    const int grid = M / ROWS;          // 2048 blocks

    pc_kernel<<<grid, THREADS, 0, stream>>>(x, w_bet, b_bet, w_stk, b_stk,
                                            w_call, b_call, w_odds, b_odds,
                                            ot, out);
}